// Round 3
// baseline (392.054 us; speedup 1.0000x reference)
//
#include <hip/hip_runtime.h>
#include <cstdint>
#include <cmath>

typedef _Float16 f16;
typedef _Float16 f16x8 __attribute__((ext_vector_type(8)));
typedef float f32x4 __attribute__((ext_vector_type(4)));

// async 16B/lane global->LDS (lds dst = wave-uniform base + lane*16)
__device__ inline void gld_lds16(const void* g, void* l) {
  __builtin_amdgcn_global_load_lds(
      (__attribute__((address_space(1))) void*)(uintptr_t)g,
      (__attribute__((address_space(3))) void*)l, 16, 0, 0);
}

// ---------------------------------------------------------------------------
// Build X1 = [enc_flat(10240) | word(512) | persona[speaker](512) | h0(512)] fp16
__global__ __launch_bounds__(256) void build_x1_kernel(
    const float* __restrict__ enc, const float* __restrict__ word,
    const float* __restrict__ pers, const int* __restrict__ speaker,
    const float* __restrict__ h0, f16* __restrict__ X)
{
  const int b  = blockIdx.y;
  const int k2 = blockIdx.x * 256 + threadIdx.x;   // 0..5887
  const int k  = k2 * 2;
  float v0, v1;
  if (k < 10240) {
    const float* p = enc + (long long)b * 10240 + k; v0 = p[0]; v1 = p[1];
  } else if (k < 10752) {
    const float* p = word + b * 512 + (k - 10240);   v0 = p[0]; v1 = p[1];
  } else if (k < 11264) {
    const float* p = pers + (long long)speaker[b] * 512 + (k - 10752); v0 = p[0]; v1 = p[1];
  } else {
    const float* p = h0 + b * 512 + (k - 11264);     v0 = p[0]; v1 = p[1];
  }
  union { f16 h[2]; unsigned int u; } pk;
  pk.h[0] = (f16)v0; pk.h[1] = (f16)v1;
  ((unsigned int*)X)[(long long)b * 5888 + k2] = pk.u;
}

// ---------------------------------------------------------------------------
// Pipelined fp16 MFMA GEMM: BM=128 BN=128 BK=32, 256 thr (4 waves 2x2,
// wave tile 64x64). Double-buffered LDS; loads for iter k+1 issued before
// compute of iter k so the barrier's vmcnt(0) drain overlaps compute.
// A fp16 via global_load_lds (chunk-swizzled rows of 32h). B fp32->fp16,
// float2/thread, [n][40] padded layout. blockIdx.z = split-K slice.
__global__ __launch_bounds__(256, 2) void gemm_f16_pipe(
    const f16* __restrict__ A, int lda,
    const float* __restrict__ B0, const float* __restrict__ B1, int ksw, int ldb,
    void* __restrict__ Cv, int ldc, long long c_split_stride, int niter,
    int store_f16)
{
  __shared__ __align__(16) f16 Ah[2][128 * 32];   // 2 x 8 KB
  __shared__ __align__(16) f16 Bh[2][128 * 40];   // 2 x 10 KB

  const int tid  = threadIdx.x;
  const int lane = tid & 63;
  const int wave = tid >> 6;
  const int m0 = blockIdx.x * 128;
  const int n0 = blockIdx.y * 128;
  const int kbeg = blockIdx.z * (niter * 32);

  // A staging lane map (verified r1/r2): lane -> row lane>>2 within 16-row
  // group, stored chunk lane&3, actual k-chunk (lane&3)^((lane>>3)&3)
  const int a_row16 = lane >> 2;
  const int a_ksub  = ((lane & 3) ^ ((lane >> 3) & 3)) * 8;

  // B staging: thread -> 2 adjacent columns, one 8-k chunk
  const int nl0  = (tid & 63) * 2;
  const int koct = tid >> 6;          // 0..3

  float2 bv[8];

  auto issueB = [&](int kt) {
    const int kb = kbeg + kt * 32 + koct * 8;
    #pragma unroll
    for (int i = 0; i < 8; i++) {
      const int krow = kb + i;
      const float* bp = (krow >= ksw) ? (B1 + (long long)(krow - ksw) * ldb)
                                      : (B0 + (long long)krow * ldb);
      bv[i] = *(const float2*)(bp + n0 + nl0);
    }
  };
  auto issueA = [&](int kt) {
    const int akb = kbeg + kt * 32;
    #pragma unroll
    for (int half = 0; half < 2; half++) {
      const int rb = wave * 32 + half * 16;
      const f16* gp = A + (long long)(m0 + rb + a_row16) * lda + akb + a_ksub;
      gld_lds16((const void*)gp, (void*)&Ah[kt & 1][rb * 32]);
    }
  };
  auto writeB = [&](int kt) {
    f16x8 p0, p1;
    #pragma unroll
    for (int i = 0; i < 8; i++) { p0[i] = (f16)bv[i].x; p1[i] = (f16)bv[i].y; }
    *(f16x8*)&Bh[kt & 1][(nl0    ) * 40 + koct * 8] = p0;
    *(f16x8*)&Bh[kt & 1][(nl0 + 1) * 40 + koct * 8] = p1;
  };

  const int wm = (wave & 1) * 64;
  const int wn = (wave >> 1) * 64;
  f32x4 acc[4][4] = {};

  issueB(0); issueA(0); writeB(0);
  __syncthreads();

  for (int kt = 0; kt < niter; kt++) {
    const int buf = kt & 1;
    const bool more = (kt + 1 < niter);
    if (more) { issueB(kt + 1); issueA(kt + 1); }

    f16x8 af[4], bf[4];
    #pragma unroll
    for (int mi = 0; mi < 4; mi++) {
      const int m = wm + mi * 16 + (lane & 15);
      af[mi] = *(const f16x8*)&Ah[buf][m * 32 + (((lane >> 4) ^ ((m >> 1) & 3)) * 8)];
    }
    #pragma unroll
    for (int ni = 0; ni < 4; ni++) {
      const int n = wn + ni * 16 + (lane & 15);
      bf[ni] = *(const f16x8*)&Bh[buf][n * 40 + (lane >> 4) * 8];
    }
    #pragma unroll
    for (int mi = 0; mi < 4; mi++)
      #pragma unroll
      for (int ni = 0; ni < 4; ni++)
        acc[mi][ni] = __builtin_amdgcn_mfma_f32_16x16x32_f16(af[mi], bf[ni], acc[mi][ni], 0, 0, 0);

    if (more) writeB(kt + 1);
    __syncthreads();
  }

  // C/D: col = lane&15, row = (lane>>4)*4 + r
  if (store_f16) {
    f16* Cs = (f16*)Cv + (long long)blockIdx.z * c_split_stride;
    #pragma unroll
    for (int mi = 0; mi < 4; mi++) {
      const int r0 = m0 + wm + mi * 16 + (lane >> 4) * 4;
      #pragma unroll
      for (int ni = 0; ni < 4; ni++) {
        const int cc = n0 + wn + ni * 16 + (lane & 15);
        #pragma unroll
        for (int r = 0; r < 4; r++)
          Cs[(long long)(r0 + r) * ldc + cc] = (f16)acc[mi][ni][r];
      }
    }
  } else {
    float* Cs = (float*)Cv + (long long)blockIdx.z * c_split_stride;
    #pragma unroll
    for (int mi = 0; mi < 4; mi++) {
      const int r0 = m0 + wm + mi * 16 + (lane >> 4) * 4;
      #pragma unroll
      for (int ni = 0; ni < 4; ni++) {
        const int cc = n0 + wn + ni * 16 + (lane & 15);
        #pragma unroll
        for (int r = 0; r < 4; r++)
          Cs[(long long)(r0 + r) * ldc + cc] = acc[mi][ni][r];
      }
    }
  }
}

// ---------------------------------------------------------------------------
// Fused small LSTM layer: z = [h|h] @ [W;U] (K=1024), gates in-epilogue.
// Block = 64 batch rows x 16 h-cols; the 4 gate column groups (j, j+512,
// j+1024, j+1536) are computed by waves 0..3 -> no split-K partial traffic.
__global__ __launch_bounds__(256, 2) void lstm_fused_layer(
    const f16* __restrict__ A,                      // h_in fp16 [256][512]
    const float* __restrict__ W, const float* __restrict__ U,  // [512][2048]
    const float* __restrict__ bias,                 // [2048]
    const float* __restrict__ c_prev, float* __restrict__ c_out,
    f16* __restrict__ h16_out, float* __restrict__ h32_out)
{
  __shared__ __align__(16) f16 Ah[2][64 * 32];   // 2 x 4 KB
  __shared__ __align__(16) f16 Bh[2][64 * 40];   // 2 x 5 KB
  __shared__ float zx[64 * 16 * 4];              // 16 KB  (m, j, gate)

  const int tid  = threadIdx.x;
  const int lane = tid & 63;
  const int wave = tid >> 6;                     // = gate group g
  const int m0 = blockIdx.x * 64;
  const int j0 = blockIdx.y * 16;

  const int a_row4  = lane >> 2;
  const int a_ksub  = ((lane & 3) ^ ((lane >> 3) & 3)) * 8;

  // B staging: thread -> col nl = tid&63 (g' = nl>>4, j = nl&15), chunk tid>>6
  const int nl   = tid & 63;
  const int ng   = (nl >> 4) * 512 + j0 + (nl & 15);
  const int koct = tid >> 6;

  float bv[8];
  auto issueB = [&](int kt) {
    const int kb = kt * 32 + koct * 8;
    #pragma unroll
    for (int i = 0; i < 8; i++) {
      const int krow = kb + i;
      const float* bp = (krow >= 512) ? (U + (long long)(krow - 512) * 2048)
                                      : (W + (long long)krow * 2048);
      bv[i] = bp[ng];
    }
  };
  auto issueA = [&](int kt) {
    const int ak = (kt * 32 + a_ksub) & 511;
    const f16* gp = A + (long long)(m0 + wave * 16 + a_row4) * 512 + ak;
    gld_lds16((const void*)gp, (void*)&Ah[kt & 1][wave * 16 * 32]);
  };
  auto writeB = [&](int kt) {
    f16x8 p;
    #pragma unroll
    for (int i = 0; i < 8; i++) p[i] = (f16)bv[i];
    *(f16x8*)&Bh[kt & 1][nl * 40 + koct * 8] = p;
  };

  f32x4 acc[4] = {};

  issueB(0); issueA(0); writeB(0);
  __syncthreads();

  for (int kt = 0; kt < 32; kt++) {
    const int buf = kt & 1;
    const bool more = (kt + 1 < 32);
    if (more) { issueB(kt + 1); issueA(kt + 1); }

    f16x8 af[4], bfr;
    #pragma unroll
    for (int mi = 0; mi < 4; mi++) {
      const int m = mi * 16 + (lane & 15);
      af[mi] = *(const f16x8*)&Ah[buf][m * 32 + (((lane >> 4) ^ ((m >> 1) & 3)) * 8)];
    }
    bfr = *(const f16x8*)&Bh[buf][(wave * 16 + (lane & 15)) * 40 + (lane >> 4) * 8];
    #pragma unroll
    for (int mi = 0; mi < 4; mi++)
      acc[mi] = __builtin_amdgcn_mfma_f32_16x16x32_f16(af[mi], bfr, acc[mi], 0, 0, 0);

    if (more) writeB(kt + 1);
    __syncthreads();
  }

  // exchange z across waves: zx[((m*16)+j)*4 + g]
  #pragma unroll
  for (int mi = 0; mi < 4; mi++) {
    const int rbase = mi * 16 + (lane >> 4) * 4;
    #pragma unroll
    for (int r = 0; r < 4; r++)
      zx[((rbase + r) * 16 + (lane & 15)) * 4 + wave] = acc[mi][r];
  }
  __syncthreads();

  #pragma unroll
  for (int i = 0; i < 4; i++) {
    const int cell = i * 256 + tid;       // 0..1023
    const int m = cell >> 4;
    const int j = cell & 15;
    const float4 z = ((const float4*)zx)[cell];
    const float zi = z.x + bias[j0 + j];
    const float zf = z.y + bias[512 + j0 + j];
    const float zg = z.z + bias[1024 + j0 + j];
    const float zo = z.w + bias[1536 + j0 + j];
    const float gi = 1.f / (1.f + expf(-zi));
    const float gf = 1.f / (1.f + expf(-zf));
    const float gg = fmaxf(zg, 0.f);
    const float go = 1.f / (1.f + expf(-zo));
    const int idx = (m0 + m) * 512 + j0 + j;
    const float cn = gf * c_prev[idx] + gi * gg;
    const float hn = go * fmaxf(cn, 0.f);
    c_out[idx] = cn;
    h16_out[idx] = (f16)hn;
    if (h32_out) h32_out[idx] = hn;
  }
}

// ---------------------------------------------------------------------------
// L1 gate: reduce 16 fp16 split-K partials + bias, apply gates. 2 cols/thread.
__global__ __launch_bounds__(256) void gate_kernel(
    const unsigned int* __restrict__ zbase, const float* __restrict__ bias,
    const float* __restrict__ c_prev, float* __restrict__ c_out,
    f16* __restrict__ h16_out)
{
  const int idx2 = blockIdx.x * 256 + threadIdx.x;  // 0..65535
  const int b  = idx2 >> 8;
  const int j2 = idx2 & 255;          // column pair
  const int j  = j2 * 2;
  float z[4][2];
  #pragma unroll
  for (int g = 0; g < 4; g++) { z[g][0] = bias[g * 512 + j]; z[g][1] = bias[g * 512 + j + 1]; }
  for (int s = 0; s < 16; s++) {
    const unsigned int* zp = zbase + s * 262144 + b * 1024;
    #pragma unroll
    for (int g = 0; g < 4; g++) {
      union { unsigned int u; f16 h[2]; } v;
      v.u = zp[g * 256 + j2];
      z[g][0] += (float)v.h[0];
      z[g][1] += (float)v.h[1];
    }
  }
  #pragma unroll
  for (int e = 0; e < 2; e++) {
    const float gi = 1.f / (1.f + expf(-z[0][e]));
    const float gf = 1.f / (1.f + expf(-z[1][e]));
    const float gg = fmaxf(z[2][e], 0.f);
    const float go = 1.f / (1.f + expf(-z[3][e]));
    const int idx = b * 512 + j + e;
    const float cn = gf * c_prev[idx] + gi * gg;
    const float hn = go * fmaxf(cn, 0.f);
    c_out[idx] = cn;
    h16_out[idx] = (f16)hn;
  }
}

// ---------------------------------------------------------------------------
// In-place softmax over V=32000 per row, float4 path. 1024 thr/row.
__global__ __launch_bounds__(1024) void softmax_kernel(
    float* __restrict__ logits, const float* __restrict__ bd)
{
  const int row = blockIdx.x;
  const int t = threadIdx.x;
  float4* rp = (float4*)(logits + (long long)row * 32000);   // 8000 float4
  const float4* bp = (const float4*)bd;
  float4 l[8];
  float m = -1e30f;
  #pragma unroll
  for (int i = 0; i < 8; i++) {
    const int v = t + i * 1024;
    if (v < 8000) {
      float4 x = rp[v]; const float4 bb = bp[v];
      x.x += bb.x; x.y += bb.y; x.z += bb.z; x.w += bb.w;
      l[i] = x;
      m = fmaxf(m, fmaxf(fmaxf(x.x, x.y), fmaxf(x.z, x.w)));
    } else {
      l[i] = make_float4(-1e30f, -1e30f, -1e30f, -1e30f);
    }
  }
  #pragma unroll
  for (int off = 32; off > 0; off >>= 1) m = fmaxf(m, __shfl_xor(m, off, 64));
  __shared__ float redm[16];
  __shared__ float reds[16];
  const int w = t >> 6;
  if ((t & 63) == 0) redm[w] = m;
  __syncthreads();
  float bm = redm[0];
  #pragma unroll
  for (int i = 1; i < 16; i++) bm = fmaxf(bm, redm[i]);
  float s = 0.f;
  #pragma unroll
  for (int i = 0; i < 8; i++) {
    const float ex = expf(l[i].x - bm), ey = expf(l[i].y - bm);
    const float ez = expf(l[i].z - bm), ew = expf(l[i].w - bm);
    l[i] = make_float4(ex, ey, ez, ew);
    s += (ex + ey) + (ez + ew);
  }
  #pragma unroll
  for (int off = 32; off > 0; off >>= 1) s += __shfl_xor(s, off, 64);
  if ((t & 63) == 0) reds[w] = s;
  __syncthreads();
  float ts = 0.f;
  #pragma unroll
  for (int i = 0; i < 16; i++) ts += reds[i];
  const float inv = 1.0f / ts;
  #pragma unroll
  for (int i = 0; i < 8; i++) {
    const int v = t + i * 1024;
    if (v < 8000) {
      float4 x = l[i];
      x.x *= inv; x.y *= inv; x.z *= inv; x.w *= inv;
      rp[v] = x;
    }
  }
}

// ---------------------------------------------------------------------------
extern "C" void kernel_launch(void* const* d_in, const int* in_sizes, int n_in,
                              void* d_out, int out_size, void* d_ws, size_t ws_size,
                              hipStream_t stream) {
  const float* enc     = (const float*)d_in[0];
  const float* word    = (const float*)d_in[1];
  const float* h0      = (const float*)d_in[2];
  const float* c0      = (const float*)d_in[3];
  const int*   speaker = (const int*)d_in[4];
  const float* pers = (const float*)d_in[6];
  const float* W1 = (const float*)d_in[7];
  const float* U1 = (const float*)d_in[8];
  const float* b1 = (const float*)d_in[9];
  const float* W2 = (const float*)d_in[10];
  const float* U2 = (const float*)d_in[11];
  const float* b2 = (const float*)d_in[12];
  const float* W3 = (const float*)d_in[13];
  const float* U3 = (const float*)d_in[14];
  const float* b3 = (const float*)d_in[15];
  const float* W4 = (const float*)d_in[16];
  const float* U4 = (const float*)d_in[17];
  const float* b4 = (const float*)d_in[18];
  const float* Wd = (const float*)d_in[19];
  const float* bd = (const float*)d_in[20];

  float* out = (float*)d_out;
  // d_out scratch use (all consumed before decoder writes logits over [0,32.77MB)):
  //   [0, 16 MB)       : 16 fp16 split-K z partials (1 MB each)
  //   [16 MB, 22.8 MB) : X1 fp16 (256 x 11776)
  //   [24 MB, 24.5 MB) : c chain buffer (fp32, 256x512)
  f16*   zp16  = (f16*)d_out;
  f16*   X1h   = (f16*)((char*)d_out + 16777216);
  float* cbuf  = out + 6291456;            // 24 MB
  float* h4_out = out + 8192000;
  float* c4_out = out + 8192000 + 131072;

  f16* hA = (f16*)d_ws;                          // 256 KB
  f16* hB = (f16*)((char*)d_ws + 262144);        // 256 KB
  f16* hC = (f16*)((char*)d_ws + 524288);        // 256 KB

  const int BIG = 1 << 29;

  build_x1_kernel<<<dim3(23, 256), 256, 0, stream>>>(enc, word, pers, speaker, h0, X1h);

  // layer 1: K = 11264 (W1) + 512 (U1) = 16 x 736; grid 2x16x16 = 512 blocks
  gemm_f16_pipe<<<dim3(2, 16, 16), 256, 0, stream>>>(
      X1h, 11776, W1, U1, 11264, 2048, zp16, 2048, 524288LL, 23, 1);
  gate_kernel<<<dim3(256), 256, 0, stream>>>((const unsigned int*)zp16, b1, c0, cbuf, hA);

  // layers 2-4 fused (grid 4 m-blocks x 32 j-blocks = 128 blocks)
  lstm_fused_layer<<<dim3(4, 32), 256, 0, stream>>>(hA, W2, U2, b2, cbuf, cbuf, hB, nullptr);
  lstm_fused_layer<<<dim3(4, 32), 256, 0, stream>>>(hB, W3, U3, b3, cbuf, cbuf, hA, nullptr);
  lstm_fused_layer<<<dim3(4, 32), 256, 0, stream>>>(hA, W4, U4, b4, cbuf, c4_out, hC, h4_out);

  // decoder: logits = h4 @ Wd, fp32 in place; grid 2x250 = 500 blocks
  gemm_f16_pipe<<<dim3(2, 250, 1), 256, 0, stream>>>(
      hC, 512, Wd, Wd, BIG, 32000, out, 32000, 0LL, 16, 0);

  softmax_kernel<<<dim3(256), 1024, 0, stream>>>(out, bd);
}